// Round 1
// baseline (3928.054 us; speedup 1.0000x reference)
//
#include <hip/hip_runtime.h>
#include <cstdint>
#include <cstddef>

// Problem constants
#define TT 1024
#define NB 64
#define HD 256
#define NG 768   // 3*H

typedef short bhalf8 __attribute__((ext_vector_type(8)));   // 8 bf16 (4 VGPRs)
typedef float f32x4  __attribute__((ext_vector_type(4)));   // MFMA accumulator

__device__ __forceinline__ unsigned short f2bf(float f) {
  unsigned u = __float_as_uint(f);
  unsigned r = (u + 0x7FFFu + ((u >> 16) & 1u)) >> 16;   // RNE
  return (unsigned short)r;
}
__device__ __forceinline__ float bf2f(unsigned short s) {
  return __uint_as_float(((unsigned)s) << 16);
}
__device__ __forceinline__ float sigm(float x) { return 1.0f / (1.0f + __expf(-x)); }
__device__ __forceinline__ float tanh_fast(float x) {
  // exact identity tanh(x) = 1 - 2/(e^{2x}+1); robust at +-inf
  return 1.0f - 2.0f / (__expf(2.0f * x) + 1.0f);
}

// ---------------------------------------------------------------------------
// Kernel 1: gx[dir][t][g][b] (bf16) = sum_k X[b,t,k]*wih[g,k] + bih[g]+bhh[g]
// Layout [t][g][b] chosen so the recurrent kernel's per-lane gx loads are
// ushort4 (4 consecutive batch elems == 4 accumulator regs of one D tile).
// ---------------------------------------------------------------------------
__launch_bounds__(256, 2)
__global__ void gx_kernel(const float* __restrict__ X,
                          const float* __restrict__ wih_f, const float* __restrict__ bih_f,
                          const float* __restrict__ bhh_f,
                          const float* __restrict__ wih_b, const float* __restrict__ bih_b,
                          const float* __restrict__ bhh_b,
                          unsigned short* __restrict__ gx) {
  const int tid = threadIdx.x;
  const int n0  = blockIdx.x * 64;     // gate-col tile
  const int t   = blockIdx.y;
  const int dir = blockIdx.z;
  const float* wih = dir ? wih_b : wih_f;
  const float* bih = dir ? bih_b : bih_f;
  const float* bhh = dir ? bhh_b : bhh_f;
  unsigned short* gxd = gx + (size_t)dir * (size_t)TT * NG * NB;

  __shared__ unsigned short Al[64][264];   // X tile   [b][k], pad for banks
  __shared__ unsigned short Bl[64][264];   // wih tile [g][k]

  // Stage full K=256 tiles once (fp32 -> bf16)
#pragma unroll
  for (int i = 0; i < 16; ++i) {
    int f4  = tid + i * 256;        // 4096 float4 total
    int row = f4 >> 6;              // 64 float4 per row
    int kk  = (f4 & 63) * 4;
    float4 xv = *(const float4*)(X + ((size_t)row * TT + t) * HD + kk);
    Al[row][kk + 0] = f2bf(xv.x); Al[row][kk + 1] = f2bf(xv.y);
    Al[row][kk + 2] = f2bf(xv.z); Al[row][kk + 3] = f2bf(xv.w);
    float4 wv = *(const float4*)(wih + (size_t)(n0 + row) * HD + kk);
    Bl[row][kk + 0] = f2bf(wv.x); Bl[row][kk + 1] = f2bf(wv.y);
    Bl[row][kk + 2] = f2bf(wv.z); Bl[row][kk + 3] = f2bf(wv.w);
  }
  __syncthreads();

  const int lane = tid & 63, w = tid >> 6, quad = lane >> 4, l15 = lane & 15;

  f32x4 acc[4];
#pragma unroll
  for (int jt = 0; jt < 4; ++jt) { acc[jt][0]=0.f; acc[jt][1]=0.f; acc[jt][2]=0.f; acc[jt][3]=0.f; }

#pragma unroll
  for (int kt = 0; kt < 8; ++kt) {
    bhalf8 a = *(const bhalf8*)&Al[16 * w + l15][kt * 32 + quad * 8];
#pragma unroll
    for (int jt = 0; jt < 4; ++jt) {
      bhalf8 b = *(const bhalf8*)&Bl[jt * 16 + l15][kt * 32 + quad * 8];
      acc[jt] = __builtin_amdgcn_mfma_f32_16x16x32_bf16(a, b, acc[jt], 0, 0, 0);
    }
  }

#pragma unroll
  for (int jt = 0; jt < 4; ++jt) {
    int g = n0 + jt * 16 + l15;
    float bias = bih[g] + bhh[g];
#pragma unroll
    for (int r = 0; r < 4; ++r) {
      int b = 16 * w + quad * 4 + r;        // D layout: row = quad*4+reg
      gxd[((size_t)t * NG + g) * NB + b] = f2bf(acc[jt][r] + bias);
    }
  }
}

// ---------------------------------------------------------------------------
// Kernel 2: recurrence. 8 blocks = 2 dirs x 4 batch-slices of 16.
// 512 threads = 8 waves; wave w owns h-cols [32w,32w+32) i.e. gate rows
// {hc, 256+hc, 512+hc}. W_hh fragments: 40 in VGPRs + 8 (og,jn=1) in LDS.
// h exchanged via double-buffered LDS; c in fp32 registers. gx prefetched
// one step ahead directly into D-layout ushort4.
// ---------------------------------------------------------------------------
__launch_bounds__(512, 2)
__global__ void rec_kernel(const float* __restrict__ whh_f,
                           const float* __restrict__ whh_b,
                           const unsigned short* __restrict__ gx,
                           float* __restrict__ out) {
  const int tid  = threadIdx.x;
  const int lane = tid & 63, w = tid >> 6, quad = lane >> 4, l15 = lane & 15;
  const int blk = blockIdx.x;          // 0..7
  const int dir = blk >> 2;
  const int b0  = (blk & 3) * 16;
  const float* whh = dir ? whh_b : whh_f;
  const unsigned short* gxd = gx + (size_t)dir * (size_t)TT * NG * NB;
  float* hn = out + (size_t)TT * NB * 512;
  float* cn = hn + (size_t)NB * 512;

  __shared__ uint4 wlds[8][8][64];             // 64 KB: [wave][kt][lane]
  __shared__ unsigned short hbuf[2][16][264];  // 16.9 KB, pad 264 -> 528B rows

  // ---- load W_hh fragments (one-time) ----
  uint4 wreg[5][8];
#pragma unroll
  for (int p = 0; p < 6; ++p) {              // p = g3*2 + jn
    int n = (p >> 1) * 256 + 32 * w + (p & 1) * 16 + l15;   // gate row
#pragma unroll
    for (int kt = 0; kt < 8; ++kt) {
      const float* wp = whh + (size_t)n * HD + kt * 32 + quad * 8;
      float4 v0 = *(const float4*)wp;
      float4 v1 = *(const float4*)(wp + 4);
      union { unsigned short us[8]; uint4 u; } pk;
      pk.us[0] = f2bf(v0.x); pk.us[1] = f2bf(v0.y); pk.us[2] = f2bf(v0.z); pk.us[3] = f2bf(v0.w);
      pk.us[4] = f2bf(v1.x); pk.us[5] = f2bf(v1.y); pk.us[6] = f2bf(v1.z); pk.us[7] = f2bf(v1.w);
      if (p < 5) wreg[p][kt] = pk.u;
      else       wlds[w][kt][lane] = pk.u;
    }
  }

  // zero h_0 buffer
  for (int i = tid; i < 16 * 264; i += 512) ((unsigned short*)hbuf)[i] = 0;

  float cstate[2][4];
#pragma unroll
  for (int jn = 0; jn < 2; ++jn)
#pragma unroll
    for (int r = 0; r < 4; ++r) cstate[jn][r] = 0.0f;

  int goff[6];
#pragma unroll
  for (int p = 0; p < 6; ++p) {
    int g = (p >> 1) * 256 + 32 * w + (p & 1) * 16 + l15;
    goff[p] = g * NB + b0 + quad * 4;
  }

  __syncthreads();

  // initial gx prefetch (s = 0)
  ushort4 gxv[6];
  {
    size_t tb = (size_t)(dir ? (TT - 1) : 0) * NG * NB;
#pragma unroll
    for (int p = 0; p < 6; ++p) gxv[p] = *(const ushort4*)(gxd + tb + goff[p]);
  }

  for (int s = 0; s < TT; ++s) {
    const int tr = dir ? (TT - 1 - s) : s;
    const int pb = s & 1;

    // accumulator init straight from gx (D layout matches ushort4 lanes)
    f32x4 acc[6];
#pragma unroll
    for (int p = 0; p < 6; ++p) {
      acc[p][0] = bf2f(gxv[p].x); acc[p][1] = bf2f(gxv[p].y);
      acc[p][2] = bf2f(gxv[p].z); acc[p][3] = bf2f(gxv[p].w);
    }
    // prefetch next step's gx; in flight during the MFMA phase
    if (s + 1 < TT) {
      size_t tb = (size_t)(dir ? (TT - 2 - s) : (s + 1)) * NG * NB;
#pragma unroll
      for (int p = 0; p < 6; ++p) gxv[p] = *(const ushort4*)(gxd + tb + goff[p]);
    }

    // gates += h @ W_hh^T
#pragma unroll
    for (int kt = 0; kt < 8; ++kt) {
      bhalf8 a = *(const bhalf8*)&hbuf[pb][l15][kt * 32 + quad * 8];
#pragma unroll
      for (int p = 0; p < 5; ++p)
        acc[p] = __builtin_amdgcn_mfma_f32_16x16x32_bf16(
            a, __builtin_bit_cast(bhalf8, wreg[p][kt]), acc[p], 0, 0, 0);
      acc[5] = __builtin_amdgcn_mfma_f32_16x16x32_bf16(
          a, __builtin_bit_cast(bhalf8, wlds[w][kt][lane]), acc[5], 0, 0, 0);
    }

    // epilogue: coupled-gate update
#pragma unroll
    for (int jn = 0; jn < 2; ++jn) {
#pragma unroll
      for (int r = 0; r < 4; ++r) {
        float ig = sigm(acc[jn][r]);
        float cg = tanh_fast(acc[2 + jn][r]);
        float og = sigm(acc[4 + jn][r]);
        float cv = (1.0f - ig) * cstate[jn][r] + ig * cg;
        cstate[jn][r] = cv;
        float hv = og * tanh_fast(cv);
        int col  = 32 * w + jn * 16 + l15;
        int brow = b0 + quad * 4 + r;
        out[((size_t)tr * NB + brow) * 512 + dir * 256 + col] = hv;
        hbuf[pb ^ 1][quad * 4 + r][col] = f2bf(hv);
        if (s == TT - 1) {
          hn[(size_t)brow * 512 + dir * 256 + col] = hv;
          cn[(size_t)brow * 512 + dir * 256 + col] = cv;
        }
      }
    }
    __syncthreads();   // h_{s+1} published before next step's A reads
  }
}

// ---------------------------------------------------------------------------
extern "C" void kernel_launch(void* const* d_in, const int* in_sizes, int n_in,
                              void* d_out, int out_size, void* d_ws, size_t ws_size,
                              hipStream_t stream) {
  const float* X     = (const float*)d_in[0];
  const float* wih_f = (const float*)d_in[1];
  const float* whh_f = (const float*)d_in[2];
  const float* bih_f = (const float*)d_in[3];
  const float* bhh_f = (const float*)d_in[4];
  const float* wih_b = (const float*)d_in[5];
  const float* whh_b = (const float*)d_in[6];
  const float* bih_b = (const float*)d_in[7];
  const float* bhh_b = (const float*)d_in[8];
  float* out = (float*)d_out;
  unsigned short* gxbuf = (unsigned short*)d_ws;   // needs 2*1024*768*64*2B = 192 MiB

  dim3 g1(NG / 64, TT, 2);
  gx_kernel<<<g1, 256, 0, stream>>>(X, wih_f, bih_f, bhh_f, wih_b, bih_b, bhh_b, gxbuf);
  rec_kernel<<<8, 512, 0, stream>>>(whh_f, whh_b, gxbuf, out);
}